// Round 3
// baseline (284.680 us; speedup 1.0000x reference)
//
#include <hip/hip_runtime.h>
#include <hip/hip_bf16.h>
#include <cstdint>
#include <cstddef>

typedef __hip_bfloat16 bf16;
typedef __attribute__((ext_vector_type(8))) short bf16x8;
typedef __attribute__((ext_vector_type(4))) float floatx4;

static constexpr int Bb = 2;
static constexpr int Ls = 4096;
static constexpr int Dm = 1024;
static constexpr int Hn = 16;
static constexpr int HD = 64;
static constexpr int BS = 256;
static constexpr int QKVROW = 3 * Dm;  // 3072

__device__ __forceinline__ short f2bf(float f) {
  union { __hip_bfloat16 b; short s; } u;
  u.b = __float2bfloat16(f);
  return u.s;
}

// Load 8 consecutive elements as a bf16x8 fragment (converting if fp32).
__device__ __forceinline__ bf16x8 load8(const bf16* p) {
  return *(const bf16x8*)(const void*)p;
}
__device__ __forceinline__ bf16x8 load8(const float* p) {
  const float4 f0 = *(const float4*)(const void*)p;
  const float4 f1 = *(const float4*)(const void*)(p + 4);
  bf16x8 r;
  r[0] = f2bf(f0.x); r[1] = f2bf(f0.y); r[2] = f2bf(f0.z); r[3] = f2bf(f0.w);
  r[4] = f2bf(f1.x); r[5] = f2bf(f1.y); r[6] = f2bf(f1.z); r[7] = f2bf(f1.w);
  return r;
}

__device__ __forceinline__ void storeC(bf16* C, size_t idx, float v) {
  C[idx] = __float2bfloat16(v);
}
__device__ __forceinline__ void storeC(float* C, size_t idx, float v) {
  C[idx] = v;
}

// C[m,n] = sum_k A[m,k] * B[n,k]; fp32 accum, bf16 MFMA internally.
// TA/TB in {float,bf16}; TC in {float,bf16}. M%128==0, N%128==0, K%32==0.
template <typename TA, typename TB, typename TC>
__global__ __launch_bounds__(256) void gemm_bt(
    const TA* __restrict__ A, const TB* __restrict__ Bm, TC* __restrict__ C,
    int M, int N, int K) {
  __shared__ __align__(16) short sA[128 * 32];
  __shared__ __align__(16) short sB[128 * 32];
  const int tid  = threadIdx.x;
  const int wave = tid >> 6, lane = tid & 63;
  const int quad = lane >> 4, l15 = lane & 15;
  const int tm = blockIdx.y * 128, tn = blockIdx.x * 128;
  const int wm = (wave >> 1) * 64, wn = (wave & 1) * 64;

  floatx4 acc[4][4];
#pragma unroll
  for (int i = 0; i < 4; i++)
#pragma unroll
    for (int j = 0; j < 4; j++) acc[i][j] = {0.f, 0.f, 0.f, 0.f};

  const int srow = tid >> 2;          // 0..63
  const int scol = (tid & 3) * 8;     // 0,8,16,24
  const TA* Ag0 = A + (size_t)(tm + srow) * K + scol;
  const TA* Ag1 = A + (size_t)(tm + srow + 64) * K + scol;
  const TB* Bg0 = Bm + (size_t)(tn + srow) * K + scol;
  const TB* Bg1 = Bm + (size_t)(tn + srow + 64) * K + scol;

  for (int kb = 0; kb < K; kb += 32) {
    // global -> registers (converted to bf16 if needed)
    const bf16x8 a0 = load8(Ag0 + kb);
    const bf16x8 a1 = load8(Ag1 + kb);
    const bf16x8 b0 = load8(Bg0 + kb);
    const bf16x8 b1 = load8(Bg1 + kb);
    __syncthreads();  // prior iteration's ds_reads complete before overwrite
    *(bf16x8*)(sA + tid * 8)        = a0;  // row srow,    k scol..scol+8
    *(bf16x8*)(sA + 2048 + tid * 8) = a1;  // row srow+64
    *(bf16x8*)(sB + tid * 8)        = b0;
    *(bf16x8*)(sB + 2048 + tid * 8) = b1;
    __syncthreads();  // LDS tile valid for all waves

    bf16x8 af[4], bfr[4];
#pragma unroll
    for (int i = 0; i < 4; i++)
      af[i] = *(const bf16x8*)(sA + (wm + i * 16 + l15) * 32 + quad * 8);
#pragma unroll
    for (int j = 0; j < 4; j++)
      bfr[j] = *(const bf16x8*)(sB + (wn + j * 16 + l15) * 32 + quad * 8);
#pragma unroll
    for (int i = 0; i < 4; i++)
#pragma unroll
      for (int j = 0; j < 4; j++)
        acc[i][j] = __builtin_amdgcn_mfma_f32_16x16x32_bf16(af[i], bfr[j], acc[i][j], 0, 0, 0);
  }

#pragma unroll
  for (int i = 0; i < 4; i++)
#pragma unroll
    for (int j = 0; j < 4; j++)
#pragma unroll
      for (int r = 0; r < 4; r++) {
        const int row = tm + wm + i * 16 + quad * 4 + r;  // C/D: row=quad*4+r
        const int col = tn + wn + j * 16 + l15;           //      col=lane&15
        storeC(C, (size_t)row * N + col, acc[i][j][r]);
      }
}

// In-place NeoX RoPE on q,k planes of the internal bf16 qkv buffer.
// thread -> (vec, j): vec = ((b*L + l)*2 + t)*H + h, j in [0,32)
// In-place safe: each 64-elem vector is handled by 32 lanes of ONE wave;
// wave loads complete (vmcnt wait) before its stores issue.
__global__ void rope_kernel(bf16* __restrict__ qkv) {
  const int t   = blockIdx.x * 256 + threadIdx.x;
  const int j   = t & 31;
  const int vec = t >> 5;
  const int h   = vec & (Hn - 1);
  const int tq  = (vec >> 4) & 1;
  const int l   = (vec >> 5) & (Ls - 1);
  const int b   = vec >> 17;
  bf16* base = qkv + (size_t)(b * Ls + l) * QKVROW + tq * Dm + h * HD;
  const unsigned u = *(const unsigned*)(const void*)(base + 2 * j);  // x[2j], x[2j+1]
  const float x1 = __uint_as_float((u & 0xFFFFu) << 16);
  const float x2 = __uint_as_float(u & 0xFFFF0000u);
  // inv_freq[j] = 10000^(-2j/64); log2(10000) = 13.2877123795
  const float freq = exp2f(-13.287712379549449f * (float)(2 * j) * (1.0f / 64.0f));
  const float ang = (float)l * freq;
  const float c = cosf(ang), s = sinf(ang);
  base[j]      = __float2bfloat16(x1 * c - x2 * s);
  base[j + 32] = __float2bfloat16(x2 * c + x1 * s);
}

// One block per (blk, h, b): 256x256 causal attention within the block.
// Wave w owns q-rows [64w, 64w+64), loops key-chunks kc=0..w (online softmax).
__global__ __launch_bounds__(256) void attn_kernel(const bf16* __restrict__ qkv,
                                                   bf16* __restrict__ aout) {
  constexpr float SCALE = 0.125f;  // 64^-0.5
  constexpr float LOG2E = 1.4426950408889634f;
  __shared__ __align__(16) short vT[HD * BS];     // vT[d][key]
  __shared__ __align__(16) short pS[4][64 * 64];  // per-wave P scratch
  const int blk = blockIdx.x, h = blockIdx.y, b = blockIdx.z;
  const int tid = threadIdx.x;
  const int wave = tid >> 6, lane = tid & 63;
  const int quad = lane >> 4, l15 = lane & 15;
  const size_t row0 = (size_t)(b * Ls + blk * BS);
  const bf16* qkvR = qkv + row0 * QKVROW;

  // stage V^T: thread tid handles key = tid (full 64-d row -> transposed scatter)
  {
    const bf16* vrow = qkvR + (size_t)tid * QKVROW + 2 * Dm + h * HD;
#pragma unroll
    for (int i = 0; i < 8; i++) {
      bf16x8 vv = *(const bf16x8*)(vrow + i * 8);
#pragma unroll
      for (int e = 0; e < 8; e++) vT[(i * 8 + e) * BS + tid] = vv[e];
    }
  }

  // q fragments in registers: A-layout m=lane&15, k=quad*8+j, 2 k-steps of 32
  bf16x8 qf[4][2];
#pragma unroll
  for (int mt = 0; mt < 4; mt++)
#pragma unroll
    for (int ks = 0; ks < 2; ks++)
      qf[mt][ks] = *(const bf16x8*)(qkvR + (size_t)(wave * 64 + mt * 16 + l15) * QKVROW
                                    + h * HD + ks * 32 + quad * 8);

  float m_i[4][4], l_i[4][4];
  floatx4 o[4][4];
#pragma unroll
  for (int mt = 0; mt < 4; mt++)
#pragma unroll
    for (int r = 0; r < 4; r++) { m_i[mt][r] = -1e30f; l_i[mt][r] = 0.f; }
#pragma unroll
  for (int mt = 0; mt < 4; mt++)
#pragma unroll
    for (int nt = 0; nt < 4; nt++) o[mt][nt] = {0.f, 0.f, 0.f, 0.f};

  __syncthreads();  // vT ready (no block barrier past this point: waves diverge in trip count)

  short* myP = &pS[wave][0];

  for (int kc = 0; kc <= wave; kc++) {
    floatx4 s[4][4];
#pragma unroll
    for (int mt = 0; mt < 4; mt++)
#pragma unroll
      for (int nt = 0; nt < 4; nt++) s[mt][nt] = {0.f, 0.f, 0.f, 0.f};

    bf16x8 kf[4][2];
#pragma unroll
    for (int nt = 0; nt < 4; nt++)
#pragma unroll
      for (int ks = 0; ks < 2; ks++)
        kf[nt][ks] = *(const bf16x8*)(qkvR + (size_t)(kc * 64 + nt * 16 + l15) * QKVROW
                                      + Dm + h * HD + ks * 32 + quad * 8);

#pragma unroll
    for (int mt = 0; mt < 4; mt++)
#pragma unroll
      for (int nt = 0; nt < 4; nt++) {
        s[mt][nt] = __builtin_amdgcn_mfma_f32_16x16x32_bf16(qf[mt][0], kf[nt][0], s[mt][nt], 0, 0, 0);
        s[mt][nt] = __builtin_amdgcn_mfma_f32_16x16x32_bf16(qf[mt][1], kf[nt][1], s[mt][nt], 0, 0, 0);
      }

    const bool diag = (kc == wave);
#pragma unroll
    for (int mt = 0; mt < 4; mt++)
#pragma unroll
      for (int r = 0; r < 4; r++) {
        const int lrow = mt * 16 + quad * 4 + r;
        float cmax = -1e30f;
#pragma unroll
        for (int nt = 0; nt < 4; nt++) {
          float sv = s[mt][nt][r] * SCALE;
          if (diag && (nt * 16 + l15 > lrow)) sv = -1e30f;
          s[mt][nt][r] = sv;
          cmax = fmaxf(cmax, sv);
        }
#pragma unroll
        for (int off = 1; off < 16; off <<= 1)
          cmax = fmaxf(cmax, __shfl_xor(cmax, off, 64));  // 16 lanes share a row
        const float mold = m_i[mt][r];
        const float mnew = fmaxf(mold, cmax);
        const float alpha = exp2f((mold - mnew) * LOG2E);
        float rsum = 0.f;
#pragma unroll
        for (int nt = 0; nt < 4; nt++) {
          const float p = exp2f((s[mt][nt][r] - mnew) * LOG2E);
          s[mt][nt][r] = p;
          rsum += p;
        }
#pragma unroll
        for (int off = 1; off < 16; off <<= 1)
          rsum += __shfl_xor(rsum, off, 64);
        l_i[mt][r] = l_i[mt][r] * alpha + rsum;
        m_i[mt][r] = mnew;
#pragma unroll
        for (int nt = 0; nt < 4; nt++) o[mt][nt][r] *= alpha;
      }

    // P: C-layout -> LDS -> A-layout (wave-private buffer, no block barrier needed)
#pragma unroll
    for (int mt = 0; mt < 4; mt++)
#pragma unroll
      for (int nt = 0; nt < 4; nt++)
#pragma unroll
        for (int r = 0; r < 4; r++)
          myP[(mt * 16 + quad * 4 + r) * 64 + nt * 16 + l15] = f2bf(s[mt][nt][r]);

    __asm__ __volatile__("s_waitcnt lgkmcnt(0)" ::: "memory");

#pragma unroll
    for (int mt = 0; mt < 4; mt++) {
      const bf16x8 pf0 = *(const bf16x8*)(myP + (mt * 16 + l15) * 64 + quad * 8);
      const bf16x8 pf1 = *(const bf16x8*)(myP + (mt * 16 + l15) * 64 + 32 + quad * 8);
#pragma unroll
      for (int nt = 0; nt < 4; nt++) {
        const bf16x8 vf0 = *(const bf16x8*)(vT + (nt * 16 + l15) * BS + kc * 64 + quad * 8);
        const bf16x8 vf1 = *(const bf16x8*)(vT + (nt * 16 + l15) * BS + kc * 64 + 32 + quad * 8);
        o[mt][nt] = __builtin_amdgcn_mfma_f32_16x16x32_bf16(pf0, vf0, o[mt][nt], 0, 0, 0);
        o[mt][nt] = __builtin_amdgcn_mfma_f32_16x16x32_bf16(pf1, vf1, o[mt][nt], 0, 0, 0);
      }
    }
  }

  // normalize and store (B,L,H,HD) -> row-major (B*L, 1024)
#pragma unroll
  for (int mt = 0; mt < 4; mt++)
#pragma unroll
    for (int r = 0; r < 4; r++) {
      const float inv = 1.0f / l_i[mt][r];
#pragma unroll
      for (int nt = 0; nt < 4; nt++) o[mt][nt][r] *= inv;
    }
#pragma unroll
  for (int mt = 0; mt < 4; mt++)
#pragma unroll
    for (int nt = 0; nt < 4; nt++)
#pragma unroll
      for (int r = 0; r < 4; r++) {
        const size_t m = row0 + wave * 64 + mt * 16 + quad * 4 + r;
        aout[m * Dm + h * HD + nt * 16 + l15] = __float2bfloat16(o[mt][nt][r]);
      }
}

extern "C" void kernel_launch(void* const* d_in, const int* in_sizes, int n_in,
                              void* d_out, int out_size, void* d_ws, size_t ws_size,
                              hipStream_t stream) {
  const float* x    = (const float*)d_in[0];   // (2,4096,1024) fp32
  const float* Wqkv = (const float*)d_in[1];   // (3072,1024) fp32
  const float* Wout = (const float*)d_in[2];   // (1024,1024) fp32
  float* out = (float*)d_out;                  // (2,4096,1024) fp32
  bf16* qkv  = (bf16*)d_ws;                    // internal: 8192 x 3072 bf16 = 50.3 MB
  bf16* attn = qkv + (size_t)8192 * 3072;      // internal: 8192 x 1024 bf16 = 16.8 MB

  // qkv = x @ Wqkv^T   (M=8192, N=3072, K=1024), fp32 in -> bf16 out
  gemm_bt<float, float, bf16>
      <<<dim3(3072 / 128, 8192 / 128), 256, 0, stream>>>(x, Wqkv, qkv, 8192, 3072, 1024);
  // RoPE in place on q,k planes: 2*4096*2*16 vectors * 32 threads
  rope_kernel<<<(Bb * Ls * 2 * Hn * 32) / 256, 256, 0, stream>>>(qkv);
  // block-causal attention: grid (nb, H, B), bf16 in -> bf16 out
  attn_kernel<<<dim3(Ls / BS, Hn, Bb), 256, 0, stream>>>(qkv, attn);
  // out = attn @ Wout^T (M=8192, N=1024, K=1024), bf16 x fp32 -> fp32 out
  gemm_bt<bf16, float, float>
      <<<dim3(1024 / 128, 8192 / 128), 256, 0, stream>>>(attn, Wout, out, 8192, 1024, 1024);
}

// Round 4
// 261.918 us; speedup vs baseline: 1.0869x; 1.0869x over previous
//
#include <hip/hip_runtime.h>
#include <hip/hip_bf16.h>
#include <cstdint>
#include <cstddef>

typedef __hip_bfloat16 bf16;
typedef __attribute__((ext_vector_type(8))) short bf16x8;
typedef __attribute__((ext_vector_type(4))) float floatx4;

static constexpr int Bb = 2;
static constexpr int Ls = 4096;
static constexpr int Dm = 1024;
static constexpr int Hn = 16;
static constexpr int HD = 64;
static constexpr int BS = 256;
static constexpr int QKVROW = 3 * Dm;  // 3072

__device__ __forceinline__ void async_load16(const void* g, void* l) {
  __builtin_amdgcn_global_load_lds(
      (__attribute__((address_space(1))) void*)(void*)(g),
      (__attribute__((address_space(3))) void*)(l), 16, 0, 0);
}

__device__ __forceinline__ short f2bf(float f) {
  union { __hip_bfloat16 b; short s; } u;
  u.b = __float2bfloat16(f);
  return u.s;
}

__device__ __forceinline__ bf16x8 load8(const bf16* p) {
  return *(const bf16x8*)(const void*)p;
}
__device__ __forceinline__ bf16x8 load8(const float* p) {
  const float4 f0 = *(const float4*)(const void*)p;
  const float4 f1 = *(const float4*)(const void*)(p + 4);
  bf16x8 r;
  r[0] = f2bf(f0.x); r[1] = f2bf(f0.y); r[2] = f2bf(f0.z); r[3] = f2bf(f0.w);
  r[4] = f2bf(f1.x); r[5] = f2bf(f1.y); r[6] = f2bf(f1.z); r[7] = f2bf(f1.w);
  return r;
}

__device__ __forceinline__ void storeC(bf16* C, size_t idx, float v) {
  C[idx] = __float2bfloat16(v);
}
__device__ __forceinline__ void storeC(float* C, size_t idx, float v) {
  C[idx] = v;
}

// fp32 -> bf16 elementwise, 8 elems/thread; n % 2048 == 0.
__global__ void cvt_kernel(const float* __restrict__ in, bf16* __restrict__ out) {
  const int i = (blockIdx.x * 256 + threadIdx.x) * 8;
  *(bf16x8*)(void*)((short*)(void*)out + i) = load8(in + i);
}

// FAST PATH GEMM: all-bf16 operands, m97 structure (global_load_lds width=16).
// C[m,n] = sum_k A[m,k]*B[n,k]; M%128==0, N%128==0, K%32==0.
template <typename TC>
__global__ __launch_bounds__(256) void gemm_bt_async(
    const bf16* __restrict__ A, const bf16* __restrict__ Bm, TC* __restrict__ C,
    int M, int N, int K) {
  __shared__ __align__(16) short sA[128 * 32];
  __shared__ __align__(16) short sB[128 * 32];
  const int tid  = threadIdx.x;
  const int wave = tid >> 6, lane = tid & 63;
  const int quad = lane >> 4, l15 = lane & 15;
  const int tm = blockIdx.y * 128, tn = blockIdx.x * 128;
  const int wm = (wave >> 1) * 64, wn = (wave & 1) * 64;

  floatx4 acc[4][4];
#pragma unroll
  for (int i = 0; i < 4; i++)
#pragma unroll
    for (int j = 0; j < 4; j++) acc[i][j] = {0.f, 0.f, 0.f, 0.f};

  const int srow = tid >> 2;          // 0..63
  const int scol = (tid & 3) * 8;     // 0,8,16,24
  const bf16* Ag0 = A + (size_t)(tm + srow) * K + scol;
  const bf16* Ag1 = A + (size_t)(tm + srow + 64) * K + scol;
  const bf16* Bg0 = Bm + (size_t)(tn + srow) * K + scol;
  const bf16* Bg1 = Bm + (size_t)(tn + srow + 64) * K + scol;
  short* sAd0 = sA + tid * 8;          // lane-contiguous (global_load_lds rule)
  short* sAd1 = sA + 2048 + tid * 8;
  short* sBd0 = sB + tid * 8;
  short* sBd1 = sB + 2048 + tid * 8;

  for (int kb = 0; kb < K; kb += 32) {
    __syncthreads();  // prior tile's ds_reads done before DMA overwrites
    async_load16(Ag0 + kb, sAd0);
    async_load16(Ag1 + kb, sAd1);
    async_load16(Bg0 + kb, sBd0);
    async_load16(Bg1 + kb, sBd1);
    __syncthreads();  // barrier drains vmcnt -> LDS tile valid

    bf16x8 af[4], bfr[4];
#pragma unroll
    for (int i = 0; i < 4; i++)
      af[i] = *(const bf16x8*)(sA + (wm + i * 16 + l15) * 32 + quad * 8);
#pragma unroll
    for (int j = 0; j < 4; j++)
      bfr[j] = *(const bf16x8*)(sB + (wn + j * 16 + l15) * 32 + quad * 8);
#pragma unroll
    for (int i = 0; i < 4; i++)
#pragma unroll
      for (int j = 0; j < 4; j++)
        acc[i][j] = __builtin_amdgcn_mfma_f32_16x16x32_bf16(af[i], bfr[j], acc[i][j], 0, 0, 0);
  }

#pragma unroll
  for (int i = 0; i < 4; i++)
#pragma unroll
    for (int j = 0; j < 4; j++)
#pragma unroll
      for (int r = 0; r < 4; r++) {
        const int row = tm + wm + i * 16 + quad * 4 + r;  // C/D: row=quad*4+r
        const int col = tn + wn + j * 16 + l15;           //      col=lane&15
        storeC(C, (size_t)row * N + col, acc[i][j][r]);
      }
}

// FALLBACK GEMM (known-good round-3): register staging, fp32-or-bf16 operands.
template <typename TA, typename TB, typename TC>
__global__ __launch_bounds__(256) void gemm_bt_reg(
    const TA* __restrict__ A, const TB* __restrict__ Bm, TC* __restrict__ C,
    int M, int N, int K) {
  __shared__ __align__(16) short sA[128 * 32];
  __shared__ __align__(16) short sB[128 * 32];
  const int tid  = threadIdx.x;
  const int wave = tid >> 6, lane = tid & 63;
  const int quad = lane >> 4, l15 = lane & 15;
  const int tm = blockIdx.y * 128, tn = blockIdx.x * 128;
  const int wm = (wave >> 1) * 64, wn = (wave & 1) * 64;

  floatx4 acc[4][4];
#pragma unroll
  for (int i = 0; i < 4; i++)
#pragma unroll
    for (int j = 0; j < 4; j++) acc[i][j] = {0.f, 0.f, 0.f, 0.f};

  const int srow = tid >> 2;
  const int scol = (tid & 3) * 8;
  const TA* Ag0 = A + (size_t)(tm + srow) * K + scol;
  const TA* Ag1 = A + (size_t)(tm + srow + 64) * K + scol;
  const TB* Bg0 = Bm + (size_t)(tn + srow) * K + scol;
  const TB* Bg1 = Bm + (size_t)(tn + srow + 64) * K + scol;

  for (int kb = 0; kb < K; kb += 32) {
    const bf16x8 a0 = load8(Ag0 + kb);
    const bf16x8 a1 = load8(Ag1 + kb);
    const bf16x8 b0 = load8(Bg0 + kb);
    const bf16x8 b1 = load8(Bg1 + kb);
    __syncthreads();
    *(bf16x8*)(sA + tid * 8)        = a0;
    *(bf16x8*)(sA + 2048 + tid * 8) = a1;
    *(bf16x8*)(sB + tid * 8)        = b0;
    *(bf16x8*)(sB + 2048 + tid * 8) = b1;
    __syncthreads();

    bf16x8 af[4], bfr[4];
#pragma unroll
    for (int i = 0; i < 4; i++)
      af[i] = *(const bf16x8*)(sA + (wm + i * 16 + l15) * 32 + quad * 8);
#pragma unroll
    for (int j = 0; j < 4; j++)
      bfr[j] = *(const bf16x8*)(sB + (wn + j * 16 + l15) * 32 + quad * 8);
#pragma unroll
    for (int i = 0; i < 4; i++)
#pragma unroll
      for (int j = 0; j < 4; j++)
        acc[i][j] = __builtin_amdgcn_mfma_f32_16x16x32_bf16(af[i], bfr[j], acc[i][j], 0, 0, 0);
  }

#pragma unroll
  for (int i = 0; i < 4; i++)
#pragma unroll
    for (int j = 0; j < 4; j++)
#pragma unroll
      for (int r = 0; r < 4; r++) {
        const int row = tm + wm + i * 16 + quad * 4 + r;
        const int col = tn + wn + j * 16 + l15;
        storeC(C, (size_t)row * N + col, acc[i][j][r]);
      }
}

// In-place NeoX RoPE on q,k planes of the internal bf16 qkv buffer.
__global__ void rope_kernel(bf16* __restrict__ qkv) {
  const int t   = blockIdx.x * 256 + threadIdx.x;
  const int j   = t & 31;
  const int vec = t >> 5;
  const int h   = vec & (Hn - 1);
  const int tq  = (vec >> 4) & 1;
  const int l   = (vec >> 5) & (Ls - 1);
  const int b   = vec >> 17;
  bf16* base = qkv + (size_t)(b * Ls + l) * QKVROW + tq * Dm + h * HD;
  const unsigned u = *(const unsigned*)(const void*)(base + 2 * j);  // x[2j], x[2j+1]
  const float x1 = __uint_as_float((u & 0xFFFFu) << 16);
  const float x2 = __uint_as_float(u & 0xFFFF0000u);
  const float freq = exp2f(-13.287712379549449f * (float)(2 * j) * (1.0f / 64.0f));
  const float ang = (float)l * freq;
  const float c = cosf(ang), s = sinf(ang);
  base[j]      = __float2bfloat16(x1 * c - x2 * s);
  base[j + 32] = __float2bfloat16(x2 * c + x1 * s);
}

// One block per (blk, h, b): 256x256 causal attention within the block.
// Wave w owns q-rows [64w,64w+64), loops key-chunks kc=0..w (online softmax).
// P-scratch split into 32-row halves: LDS 48KB total -> 3 blocks/CU.
__global__ __launch_bounds__(256) void attn_kernel(const bf16* __restrict__ qkv,
                                                   bf16* __restrict__ aout) {
  constexpr float SCALE = 0.125f;  // 64^-0.5
  constexpr float LOG2E = 1.4426950408889634f;
  __shared__ __align__(16) short vT[HD * BS];     // 32 KB: vT[d][key]
  __shared__ __align__(16) short pS[4][32 * 64];  // 16 KB: per-wave P half-scratch
  const int blk = blockIdx.x, h = blockIdx.y, b = blockIdx.z;
  const int tid = threadIdx.x;
  const int wave = tid >> 6, lane = tid & 63;
  const int quad = lane >> 4, l15 = lane & 15;
  const size_t row0 = (size_t)(b * Ls + blk * BS);
  const bf16* qkvR = qkv + row0 * QKVROW;

  // stage V^T: thread tid handles key = tid
  {
    const bf16* vrow = qkvR + (size_t)tid * QKVROW + 2 * Dm + h * HD;
#pragma unroll
    for (int i = 0; i < 8; i++) {
      bf16x8 vv = *(const bf16x8*)(vrow + i * 8);
#pragma unroll
      for (int e = 0; e < 8; e++) vT[(i * 8 + e) * BS + tid] = vv[e];
    }
  }

  // q fragments: A-layout m=lane&15, k=quad*8+j, 2 k-steps of 32
  bf16x8 qf[4][2];
#pragma unroll
  for (int mt = 0; mt < 4; mt++)
#pragma unroll
    for (int ks = 0; ks < 2; ks++)
      qf[mt][ks] = *(const bf16x8*)(qkvR + (size_t)(wave * 64 + mt * 16 + l15) * QKVROW
                                    + h * HD + ks * 32 + quad * 8);

  float m_i[4][4], l_i[4][4];
  floatx4 o[4][4];
#pragma unroll
  for (int mt = 0; mt < 4; mt++)
#pragma unroll
    for (int r = 0; r < 4; r++) { m_i[mt][r] = -1e30f; l_i[mt][r] = 0.f; }
#pragma unroll
  for (int mt = 0; mt < 4; mt++)
#pragma unroll
    for (int nt = 0; nt < 4; nt++) o[mt][nt] = {0.f, 0.f, 0.f, 0.f};

  __syncthreads();  // vT ready; no block barrier past this point

  short* myP = &pS[wave][0];

  for (int kc = 0; kc <= wave; kc++) {
    floatx4 s[4][4];
#pragma unroll
    for (int mt = 0; mt < 4; mt++)
#pragma unroll
      for (int nt = 0; nt < 4; nt++) s[mt][nt] = {0.f, 0.f, 0.f, 0.f};

    bf16x8 kf[4][2];
#pragma unroll
    for (int nt = 0; nt < 4; nt++)
#pragma unroll
      for (int ks = 0; ks < 2; ks++)
        kf[nt][ks] = *(const bf16x8*)(qkvR + (size_t)(kc * 64 + nt * 16 + l15) * QKVROW
                                      + Dm + h * HD + ks * 32 + quad * 8);

#pragma unroll
    for (int mt = 0; mt < 4; mt++)
#pragma unroll
      for (int nt = 0; nt < 4; nt++) {
        s[mt][nt] = __builtin_amdgcn_mfma_f32_16x16x32_bf16(qf[mt][0], kf[nt][0], s[mt][nt], 0, 0, 0);
        s[mt][nt] = __builtin_amdgcn_mfma_f32_16x16x32_bf16(qf[mt][1], kf[nt][1], s[mt][nt], 0, 0, 0);
      }

    const bool diag = (kc == wave);
#pragma unroll
    for (int mt = 0; mt < 4; mt++)
#pragma unroll
      for (int r = 0; r < 4; r++) {
        const int lrow = mt * 16 + quad * 4 + r;
        float cmax = -1e30f;
#pragma unroll
        for (int nt = 0; nt < 4; nt++) {
          float sv = s[mt][nt][r] * SCALE;
          if (diag && (nt * 16 + l15 > lrow)) sv = -1e30f;
          s[mt][nt][r] = sv;
          cmax = fmaxf(cmax, sv);
        }
#pragma unroll
        for (int off = 1; off < 16; off <<= 1)
          cmax = fmaxf(cmax, __shfl_xor(cmax, off, 64));
        const float mold = m_i[mt][r];
        const float mnew = fmaxf(mold, cmax);
        const float alpha = exp2f((mold - mnew) * LOG2E);
        float rsum = 0.f;
#pragma unroll
        for (int nt = 0; nt < 4; nt++) {
          const float p = exp2f((s[mt][nt][r] - mnew) * LOG2E);
          s[mt][nt][r] = p;
          rsum += p;
        }
#pragma unroll
        for (int off = 1; off < 16; off <<= 1)
          rsum += __shfl_xor(rsum, off, 64);
        l_i[mt][r] = l_i[mt][r] * alpha + rsum;
        m_i[mt][r] = mnew;
#pragma unroll
        for (int nt = 0; nt < 4; nt++) o[mt][nt][r] *= alpha;
      }

    // V fragments for this chunk (shared across both P halves)
    bf16x8 vf0[4], vf1[4];
#pragma unroll
    for (int nt = 0; nt < 4; nt++) {
      vf0[nt] = *(const bf16x8*)(vT + (nt * 16 + l15) * BS + kc * 64 + quad * 8);
      vf1[nt] = *(const bf16x8*)(vT + (nt * 16 + l15) * BS + kc * 64 + 32 + quad * 8);
    }

    // P: C-layout -> LDS -> A-layout, in two 32-row halves (wave-private;
    // per-wave DS ops are in-order so write-after-read within the wave is safe)
#pragma unroll
    for (int half = 0; half < 2; half++) {
#pragma unroll
      for (int mt2 = 0; mt2 < 2; mt2++) {
        const int mt = half * 2 + mt2;
#pragma unroll
        for (int nt = 0; nt < 4; nt++)
#pragma unroll
          for (int r = 0; r < 4; r++)
            myP[(mt2 * 16 + quad * 4 + r) * 64 + nt * 16 + l15] = f2bf(s[mt][nt][r]);
      }
      __asm__ __volatile__("s_waitcnt lgkmcnt(0)" ::: "memory");
#pragma unroll
      for (int mt2 = 0; mt2 < 2; mt2++) {
        const int mt = half * 2 + mt2;
        const bf16x8 pf0 = *(const bf16x8*)(myP + (mt2 * 16 + l15) * 64 + quad * 8);
        const bf16x8 pf1 = *(const bf16x8*)(myP + (mt2 * 16 + l15) * 64 + 32 + quad * 8);
#pragma unroll
        for (int nt = 0; nt < 4; nt++) {
          o[mt][nt] = __builtin_amdgcn_mfma_f32_16x16x32_bf16(pf0, vf0[nt], o[mt][nt], 0, 0, 0);
          o[mt][nt] = __builtin_amdgcn_mfma_f32_16x16x32_bf16(pf1, vf1[nt], o[mt][nt], 0, 0, 0);
        }
      }
      __asm__ __volatile__("s_waitcnt lgkmcnt(0)" ::: "memory");
    }
  }

  // normalize and store (B,L,H,HD) -> row-major (B*L, 1024)
#pragma unroll
  for (int mt = 0; mt < 4; mt++)
#pragma unroll
    for (int r = 0; r < 4; r++) {
      const float inv = 1.0f / l_i[mt][r];
#pragma unroll
      for (int nt = 0; nt < 4; nt++) o[mt][nt][r] *= inv;
    }
#pragma unroll
  for (int mt = 0; mt < 4; mt++)
#pragma unroll
    for (int nt = 0; nt < 4; nt++)
#pragma unroll
      for (int r = 0; r < 4; r++) {
        const size_t m = row0 + wave * 64 + mt * 16 + quad * 4 + r;
        aout[m * Dm + h * HD + nt * 16 + l15] = __float2bfloat16(o[mt][nt][r]);
      }
}

extern "C" void kernel_launch(void* const* d_in, const int* in_sizes, int n_in,
                              void* d_out, int out_size, void* d_ws, size_t ws_size,
                              hipStream_t stream) {
  const float* x    = (const float*)d_in[0];   // (2,4096,1024) fp32
  const float* Wqkv = (const float*)d_in[1];   // (3072,1024) fp32
  const float* Wout = (const float*)d_in[2];   // (1024,1024) fp32
  float* out = (float*)d_out;                  // (2,4096,1024) fp32

  const size_t NX = (size_t)8192 * 1024;   // x / attn elems
  const size_t NQ = (size_t)8192 * 3072;   // qkv elems
  const size_t NW1 = (size_t)3072 * 1024;  // Wqkv elems
  const size_t NW2 = (size_t)1024 * 1024;  // Wout elems
  const size_t fast_bytes = (NX + NQ + NW1 + NW2) * sizeof(bf16);  // 75.5 MB

  if (ws_size >= fast_bytes) {
    // ---- fast path: bf16 everywhere, async-LDS GEMMs ----
    bf16* xb    = (bf16*)d_ws;        // 16.8 MB; dead after QKV GEMM -> reused as attnb
    bf16* qkv   = xb + NX;            // 50.3 MB
    bf16* Wqkvb = qkv + NQ;           // 6.3 MB
    bf16* Woutb = Wqkvb + NW1;        // 2.1 MB
    bf16* attnb = xb;                 // alias (xb dead by then)

    cvt_kernel<<<NX / 2048, 256, 0, stream>>>(x, xb);
    cvt_kernel<<<NW1 / 2048, 256, 0, stream>>>(Wqkv, Wqkvb);
    cvt_kernel<<<NW2 / 2048, 256, 0, stream>>>(Wout, Woutb);

    gemm_bt_async<bf16>
        <<<dim3(3072 / 128, 8192 / 128), 256, 0, stream>>>(xb, Wqkvb, qkv, 8192, 3072, 1024);
    rope_kernel<<<(Bb * Ls * 2 * Hn * 32) / 256, 256, 0, stream>>>(qkv);
    attn_kernel<<<dim3(Ls / BS, Hn, Bb), 256, 0, stream>>>(qkv, attnb);
    gemm_bt_async<float>
        <<<dim3(1024 / 128, 8192 / 128), 256, 0, stream>>>(attnb, Woutb, out, 8192, 1024, 1024);
  } else {
    // ---- fallback: round-3 proven path (67.1 MB workspace) ----
    bf16* qkv  = (bf16*)d_ws;
    bf16* attn = qkv + NQ;
    gemm_bt_reg<float, float, bf16>
        <<<dim3(3072 / 128, 8192 / 128), 256, 0, stream>>>(x, Wqkv, qkv, 8192, 3072, 1024);
    rope_kernel<<<(Bb * Ls * 2 * Hn * 32) / 256, 256, 0, stream>>>(qkv);
    attn_kernel<<<dim3(Ls / BS, Hn, Bb), 256, 0, stream>>>(qkv, attn);
    gemm_bt_reg<bf16, float, float>
        <<<dim3(1024 / 128, 8192 / 128), 256, 0, stream>>>(attn, Wout, out, 8192, 1024, 1024);
  }
}

// Round 5
// 250.323 us; speedup vs baseline: 1.1373x; 1.0463x over previous
//
#include <hip/hip_runtime.h>
#include <hip/hip_bf16.h>
#include <cstdint>
#include <cstddef>

typedef __hip_bfloat16 bf16;
typedef __attribute__((ext_vector_type(8))) short bf16x8;
typedef __attribute__((ext_vector_type(4))) float floatx4;

static constexpr int Bb = 2;
static constexpr int Ls = 4096;
static constexpr int Dm = 1024;
static constexpr int Hn = 16;
static constexpr int HD = 64;
static constexpr int BS = 256;
static constexpr int QKVROW = 3 * Dm;  // 3072

__device__ __forceinline__ void async_load16(const void* g, void* l) {
  __builtin_amdgcn_global_load_lds(
      (__attribute__((address_space(1))) void*)(void*)(g),
      (__attribute__((address_space(3))) void*)(l), 16, 0, 0);
}

__device__ __forceinline__ short f2bf(float f) {
  union { __hip_bfloat16 b; short s; } u;
  u.b = __float2bfloat16(f);
  return u.s;
}

__device__ __forceinline__ bf16x8 load8(const bf16* p) {
  return *(const bf16x8*)(const void*)p;
}
__device__ __forceinline__ bf16x8 load8(const float* p) {
  const float4 f0 = *(const float4*)(const void*)p;
  const float4 f1 = *(const float4*)(const void*)(p + 4);
  bf16x8 r;
  r[0] = f2bf(f0.x); r[1] = f2bf(f0.y); r[2] = f2bf(f0.z); r[3] = f2bf(f0.w);
  r[4] = f2bf(f1.x); r[5] = f2bf(f1.y); r[6] = f2bf(f1.z); r[7] = f2bf(f1.w);
  return r;
}

__device__ __forceinline__ void storeC(bf16* C, size_t idx, float v) {
  C[idx] = __float2bfloat16(v);
}
__device__ __forceinline__ void storeC(float* C, size_t idx, float v) {
  C[idx] = v;
}

// fp32 -> bf16 elementwise, 8 elems/thread; n % 2048 == 0.
__global__ void cvt_kernel(const float* __restrict__ in, bf16* __restrict__ out) {
  const int i = (blockIdx.x * 256 + threadIdx.x) * 8;
  *(bf16x8*)(void*)((short*)(void*)out + i) = load8(in + i);
}

// All-bf16 GEMM, m97 structure (global_load_lds width=16).
// C[m,n] = sum_k A[m,k]*B[n,k]; M%128==0, N%128==0, K%32==0.
template <typename TC>
__global__ __launch_bounds__(256) void gemm_bt_async(
    const bf16* __restrict__ A, const bf16* __restrict__ Bm, TC* __restrict__ C,
    int M, int N, int K) {
  __shared__ __align__(16) short sA[128 * 32];
  __shared__ __align__(16) short sB[128 * 32];
  const int tid  = threadIdx.x;
  const int wave = tid >> 6, lane = tid & 63;
  const int quad = lane >> 4, l15 = lane & 15;
  const int tm = blockIdx.y * 128, tn = blockIdx.x * 128;
  const int wm = (wave >> 1) * 64, wn = (wave & 1) * 64;

  floatx4 acc[4][4];
#pragma unroll
  for (int i = 0; i < 4; i++)
#pragma unroll
    for (int j = 0; j < 4; j++) acc[i][j] = {0.f, 0.f, 0.f, 0.f};

  const int srow = tid >> 2;          // 0..63
  const int scol = (tid & 3) * 8;     // 0,8,16,24
  const bf16* Ag0 = A + (size_t)(tm + srow) * K + scol;
  const bf16* Ag1 = A + (size_t)(tm + srow + 64) * K + scol;
  const bf16* Bg0 = Bm + (size_t)(tn + srow) * K + scol;
  const bf16* Bg1 = Bm + (size_t)(tn + srow + 64) * K + scol;
  short* sAd0 = sA + tid * 8;          // lane-contiguous (global_load_lds rule)
  short* sAd1 = sA + 2048 + tid * 8;
  short* sBd0 = sB + tid * 8;
  short* sBd1 = sB + 2048 + tid * 8;

  for (int kb = 0; kb < K; kb += 32) {
    __syncthreads();  // prior tile's ds_reads done before DMA overwrites
    async_load16(Ag0 + kb, sAd0);
    async_load16(Ag1 + kb, sAd1);
    async_load16(Bg0 + kb, sBd0);
    async_load16(Bg1 + kb, sBd1);
    __syncthreads();  // barrier drains vmcnt -> LDS tile valid

    bf16x8 af[4], bfr[4];
#pragma unroll
    for (int i = 0; i < 4; i++)
      af[i] = *(const bf16x8*)(sA + (wm + i * 16 + l15) * 32 + quad * 8);
#pragma unroll
    for (int j = 0; j < 4; j++)
      bfr[j] = *(const bf16x8*)(sB + (wn + j * 16 + l15) * 32 + quad * 8);
#pragma unroll
    for (int i = 0; i < 4; i++)
#pragma unroll
      for (int j = 0; j < 4; j++)
        acc[i][j] = __builtin_amdgcn_mfma_f32_16x16x32_bf16(af[i], bfr[j], acc[i][j], 0, 0, 0);
  }

#pragma unroll
  for (int i = 0; i < 4; i++)
#pragma unroll
    for (int j = 0; j < 4; j++)
#pragma unroll
      for (int r = 0; r < 4; r++) {
        const int row = tm + wm + i * 16 + quad * 4 + r;  // C/D: row=quad*4+r
        const int col = tn + wn + j * 16 + l15;           //      col=lane&15
        storeC(C, (size_t)row * N + col, acc[i][j][r]);
      }
}

// In-place NeoX RoPE on q,k planes of the internal bf16 qkv buffer.
__global__ void rope_kernel(bf16* __restrict__ qkv) {
  const int t   = blockIdx.x * 256 + threadIdx.x;
  const int j   = t & 31;
  const int vec = t >> 5;
  const int h   = vec & (Hn - 1);
  const int tq  = (vec >> 4) & 1;
  const int l   = (vec >> 5) & (Ls - 1);
  const int b   = vec >> 17;
  bf16* base = qkv + (size_t)(b * Ls + l) * QKVROW + tq * Dm + h * HD;
  const unsigned u = *(const unsigned*)(const void*)(base + 2 * j);  // x[2j], x[2j+1]
  const float x1 = __uint_as_float((u & 0xFFFFu) << 16);
  const float x2 = __uint_as_float(u & 0xFFFF0000u);
  const float freq = exp2f(-13.287712379549449f * (float)(2 * j) * (1.0f / 64.0f));
  const float ang = (float)l * freq;
  const float c = cosf(ang), s = sinf(ang);
  base[j]      = __float2bfloat16(x1 * c - x2 * s);
  base[j + 32] = __float2bfloat16(x2 * c + x1 * s);
}

// One block per (blk, h, b): 256x256 causal attention within the block.
// BALANCED: 8 q-strips of 32 rows; wave w owns strips {w, 7-w} -> every wave
// does exactly 5 strip-chunk iterations (strip s needs s/2+1 key-chunks of 64).
__global__ __launch_bounds__(256) void attn_kernel(const bf16* __restrict__ qkv,
                                                   bf16* __restrict__ aout) {
  constexpr float SCALE = 0.125f;  // 64^-0.5
  constexpr float LOG2E = 1.4426950408889634f;
  __shared__ __align__(16) short vT[HD * BS];     // 32 KB: vT[d][key]
  __shared__ __align__(16) short pS[4][32 * 64];  // 16 KB: per-wave P scratch (32 rows)
  const int blk = blockIdx.x, h = blockIdx.y, b = blockIdx.z;
  const int tid = threadIdx.x;
  const int wave = tid >> 6, lane = tid & 63;
  const int quad = lane >> 4, l15 = lane & 15;
  const size_t row0 = (size_t)(b * Ls + blk * BS);
  const bf16* qkvR = qkv + row0 * QKVROW;

  // stage V^T: thread tid handles key = tid
  {
    const bf16* vrow = qkvR + (size_t)tid * QKVROW + 2 * Dm + h * HD;
#pragma unroll
    for (int i = 0; i < 8; i++) {
      bf16x8 vv = *(const bf16x8*)(vrow + i * 8);
#pragma unroll
      for (int e = 0; e < 8; e++) vT[(i * 8 + e) * BS + tid] = vv[e];
    }
  }
  __syncthreads();  // vT ready; no block barrier past this point

  short* myP = &pS[wave][0];

  for (int sp = 0; sp < 2; sp++) {
    const int s = sp ? (7 - wave) : wave;  // strip index 0..7
    const int qrow0 = s * 32;
    const int kcmax = s >> 1;

    // q fragments for this strip: A-layout m=lane&15, k=quad*8+j
    bf16x8 qf[2][2];
#pragma unroll
    for (int mt = 0; mt < 2; mt++)
#pragma unroll
      for (int ks = 0; ks < 2; ks++)
        qf[mt][ks] = *(const bf16x8*)(qkvR + (size_t)(qrow0 + mt * 16 + l15) * QKVROW
                                      + h * HD + ks * 32 + quad * 8);

    float m_i[2][4], l_i[2][4];
    floatx4 o[2][4];
#pragma unroll
    for (int mt = 0; mt < 2; mt++)
#pragma unroll
      for (int r = 0; r < 4; r++) { m_i[mt][r] = -1e30f; l_i[mt][r] = 0.f; }
#pragma unroll
    for (int mt = 0; mt < 2; mt++)
#pragma unroll
      for (int nt = 0; nt < 4; nt++) o[mt][nt] = {0.f, 0.f, 0.f, 0.f};

    for (int kc = 0; kc <= kcmax; kc++) {
      floatx4 sc[2][4];
#pragma unroll
      for (int mt = 0; mt < 2; mt++)
#pragma unroll
        for (int nt = 0; nt < 4; nt++) sc[mt][nt] = {0.f, 0.f, 0.f, 0.f};

      bf16x8 kf[4][2];
#pragma unroll
      for (int nt = 0; nt < 4; nt++)
#pragma unroll
        for (int ks = 0; ks < 2; ks++)
          kf[nt][ks] = *(const bf16x8*)(qkvR + (size_t)(kc * 64 + nt * 16 + l15) * QKVROW
                                        + Dm + h * HD + ks * 32 + quad * 8);

#pragma unroll
      for (int mt = 0; mt < 2; mt++)
#pragma unroll
        for (int nt = 0; nt < 4; nt++) {
          sc[mt][nt] = __builtin_amdgcn_mfma_f32_16x16x32_bf16(qf[mt][0], kf[nt][0], sc[mt][nt], 0, 0, 0);
          sc[mt][nt] = __builtin_amdgcn_mfma_f32_16x16x32_bf16(qf[mt][1], kf[nt][1], sc[mt][nt], 0, 0, 0);
        }

      const bool diag = (kc == kcmax);
#pragma unroll
      for (int mt = 0; mt < 2; mt++)
#pragma unroll
        for (int r = 0; r < 4; r++) {
          const int rowg = qrow0 + mt * 16 + quad * 4 + r;
          float cmax = -1e30f;
#pragma unroll
          for (int nt = 0; nt < 4; nt++) {
            float sv = sc[mt][nt][r] * SCALE;
            if (diag && (kc * 64 + nt * 16 + l15 > rowg)) sv = -1e30f;
            sc[mt][nt][r] = sv;
            cmax = fmaxf(cmax, sv);
          }
#pragma unroll
          for (int off = 1; off < 16; off <<= 1)
            cmax = fmaxf(cmax, __shfl_xor(cmax, off, 64));  // 16 lanes share a row
          const float mold = m_i[mt][r];
          const float mnew = fmaxf(mold, cmax);
          const float alpha = exp2f((mold - mnew) * LOG2E);
          float rsum = 0.f;
#pragma unroll
          for (int nt = 0; nt < 4; nt++) {
            const float p = exp2f((sc[mt][nt][r] - mnew) * LOG2E);
            sc[mt][nt][r] = p;
            rsum += p;
          }
#pragma unroll
          for (int off = 1; off < 16; off <<= 1)
            rsum += __shfl_xor(rsum, off, 64);
          l_i[mt][r] = l_i[mt][r] * alpha + rsum;
          m_i[mt][r] = mnew;
#pragma unroll
          for (int nt = 0; nt < 4; nt++) o[mt][nt][r] *= alpha;
        }

      // V fragments for this key-chunk
      bf16x8 vf0[4], vf1[4];
#pragma unroll
      for (int nt = 0; nt < 4; nt++) {
        vf0[nt] = *(const bf16x8*)(vT + (nt * 16 + l15) * BS + kc * 64 + quad * 8);
        vf1[nt] = *(const bf16x8*)(vT + (nt * 16 + l15) * BS + kc * 64 + 32 + quad * 8);
      }

      // P: C-layout -> LDS -> A-layout (wave-private; per-wave DS ops in-order)
#pragma unroll
      for (int mt = 0; mt < 2; mt++)
#pragma unroll
        for (int nt = 0; nt < 4; nt++)
#pragma unroll
          for (int r = 0; r < 4; r++)
            myP[(mt * 16 + quad * 4 + r) * 64 + nt * 16 + l15] = f2bf(sc[mt][nt][r]);

      __asm__ __volatile__("s_waitcnt lgkmcnt(0)" ::: "memory");

#pragma unroll
      for (int mt = 0; mt < 2; mt++) {
        const bf16x8 pf0 = *(const bf16x8*)(myP + (mt * 16 + l15) * 64 + quad * 8);
        const bf16x8 pf1 = *(const bf16x8*)(myP + (mt * 16 + l15) * 64 + 32 + quad * 8);
#pragma unroll
        for (int nt = 0; nt < 4; nt++) {
          o[mt][nt] = __builtin_amdgcn_mfma_f32_16x16x32_bf16(pf0, vf0[nt], o[mt][nt], 0, 0, 0);
          o[mt][nt] = __builtin_amdgcn_mfma_f32_16x16x32_bf16(pf1, vf1[nt], o[mt][nt], 0, 0, 0);
        }
      }
      __asm__ __volatile__("s_waitcnt lgkmcnt(0)" ::: "memory");  // reads done before next pack
    }

    // normalize and store strip (B,L,H,HD) -> row-major (B*L, 1024)
#pragma unroll
    for (int mt = 0; mt < 2; mt++)
#pragma unroll
      for (int r = 0; r < 4; r++) {
        const float inv = 1.0f / l_i[mt][r];
#pragma unroll
        for (int nt = 0; nt < 4; nt++) {
          const size_t m = row0 + qrow0 + mt * 16 + quad * 4 + r;
          aout[m * Dm + h * HD + nt * 16 + l15] = __float2bfloat16(o[mt][nt][r] * inv);
        }
      }
  }
}

extern "C" void kernel_launch(void* const* d_in, const int* in_sizes, int n_in,
                              void* d_out, int out_size, void* d_ws, size_t ws_size,
                              hipStream_t stream) {
  const float* x    = (const float*)d_in[0];   // (2,4096,1024) fp32
  const float* Wqkv = (const float*)d_in[1];   // (3072,1024) fp32
  const float* Wout = (const float*)d_in[2];   // (1024,1024) fp32
  float* out = (float*)d_out;                  // (2,4096,1024) fp32

  const size_t NX = (size_t)8192 * 1024;   // x / attn elems
  const size_t NQ = (size_t)8192 * 3072;   // qkv elems
  const size_t NW1 = (size_t)3072 * 1024;  // Wqkv elems
  const size_t NW2 = (size_t)1024 * 1024;  // Wout elems

  bf16* xb    = (bf16*)d_ws;        // 16.8 MB; dead after QKV GEMM -> reused as attnb
  bf16* qkv   = xb + NX;            // 50.3 MB
  bf16* Wqkvb = qkv + NQ;           // 6.3 MB
  bf16* Woutb = Wqkvb + NW1;        // 2.1 MB
  bf16* attnb = xb;                 // alias (xb dead by then)

  cvt_kernel<<<NX / 2048, 256, 0, stream>>>(x, xb);
  cvt_kernel<<<NW1 / 2048, 256, 0, stream>>>(Wqkv, Wqkvb);
  cvt_kernel<<<NW2 / 2048, 256, 0, stream>>>(Wout, Woutb);

  gemm_bt_async<bf16>
      <<<dim3(3072 / 128, 8192 / 128), 256, 0, stream>>>(xb, Wqkvb, qkv, 8192, 3072, 1024);
  rope_kernel<<<(Bb * Ls * 2 * Hn * 32) / 256, 256, 0, stream>>>(qkv);
  attn_kernel<<<dim3(Ls / BS, Hn, Bb), 256, 0, stream>>>(qkv, attnb);
  gemm_bt_async<float>
      <<<dim3(1024 / 128, 8192 / 128), 256, 0, stream>>>(attnb, Woutb, out, 8192, 1024, 1024);
}